// Round 3
// baseline (2548.402 us; speedup 1.0000x reference)
//
#include <hip/hip_runtime.h>

#define BB 2048
#define TT 512
#define KK 32

// merge (v2,i2) into (v,i): strict > keeps lower index on tie (np.argmax first-occurrence)
#define MRG(v, i, v2, i2) do { bool c_ = (v2) > (v); \
    v = c_ ? (v2) : (v); i = c_ ? (i2) : (i); } while (0)

__launch_bounds__(128)
__global__ void crf_kernel(const float* __restrict__ pot_g,
                           const float* __restrict__ trans,
                           const int* __restrict__ seqlen,
                           const int* __restrict__ tagidx,
                           float* __restrict__ out) {
    __shared__ __align__(16) float s_a[KK];          // alpha broadcast (wave 0)
    __shared__ __align__(16) float s_p[KK];          // p broadcast (wave 1)
    __shared__ unsigned char s_bp[TT * KK];          // backpointers (wave 0)

    const int tid  = threadIdx.x;
    const int wv   = tid >> 6;
    const int lane = tid & 63;
    const int j    = lane & 31;
    const int half = lane >> 5;
    const int i0   = half << 4;
    const int b    = blockIdx.x;

    const float* pot = pot_g + (size_t)b * (TT * KK);
    const int len  = seqlen[b];
    const int last = len - 1;
    float* out_tags = out + (size_t)b * TT;

    if (wv == 0) {
        // ================= Viterbi wave =================
        float tA[16];
#pragma unroll
        for (int k = 0; k < 16; ++k) tA[k] = trans[(i0 + k) * KK + j];

        float alpha = pot[j];
        float prCur = pot[min(1, last) * KK + j];
        float prN   = pot[min(2, last) * KK + j];

        for (int t = 1; t <= last; ++t) {
            float prN2 = pot[min(t + 2, last) * KK + j];

            s_a[j] = alpha;                      // both halves: same addr, same data
            __builtin_amdgcn_wave_barrier();     // compiler fence; DS pipe is in-order
            const float4 q0 = *(const float4*)(s_a + i0);
            const float4 q1 = *(const float4*)(s_a + i0 + 4);
            const float4 q2 = *(const float4*)(s_a + i0 + 8);
            const float4 q3 = *(const float4*)(s_a + i0 + 12);

            float sv[16] = {q0.x, q0.y, q0.z, q0.w, q1.x, q1.y, q1.z, q1.w,
                            q2.x, q2.y, q2.z, q2.w, q3.x, q3.y, q3.z, q3.w};
            int si[16];
#pragma unroll
            for (int k = 0; k < 16; ++k) { sv[k] += tA[k]; si[k] = i0 + k; }
#pragma unroll
            for (int w = 1; w < 16; w <<= 1)
#pragma unroll
                for (int k = 0; k < 16; k += 2 * w)
                    MRG(sv[k], si[k], sv[k + w], si[k + w]);
            float m = sv[0];
            int  bi = si[0];

            // cross-half: value-only shfl; winner (tie -> low half) writes bp
            float om = __shfl_xor(m, 32, 64);
            bool won = half ? (m > om) : (m >= om);
            float mm = fmaxf(m, om);
            if (won) s_bp[t * KK + j] = (unsigned char)bi;
            alpha = prCur + mm;                  // bit-exact recursion

            prCur = prN; prN = prN2;
        }

        // first-argmax of final alpha (replicated across halves)
        float bv = alpha; int bj = j;
#pragma unroll
        for (int d = 1; d < 32; d <<= 1) {
            float ov = __shfl_xor(bv, d, 64);
            int   oj = __shfl_xor(bj, d, 64);
            if (ov > bv || (ov == bv && oj < bj)) { bv = ov; bj = oj; }
        }
        if (lane == 0) out[(size_t)BB * TT + b] = bv;   // best_score

        for (int t = last + lane; t < TT; t += 64) out_tags[t] = (float)bj;

        // cooperative backtrace: row-loads + shfl chase, 32 steps/chunk
        __builtin_amdgcn_wave_barrier();
        int cur = bj;
        for (int thi = last; thi >= 1; thi -= 32) {
            int tlo = thi - 31; if (tlo < 1) tlo = 1;
            int nn = thi - tlo + 1;
            int rv[32];
#pragma unroll
            for (int r = 0; r < 32; ++r) {
                int t = tlo + r; t = t > thi ? thi : t;
                rv[r] = s_bp[t * KK + (lane & 31)];
            }
            int tagreg = 0;
#pragma unroll
            for (int r = 31; r >= 0; --r) {
                if (r < nn) {                       // wave-uniform predicate
                    cur = __shfl(rv[r], cur, 64);   // cur = bp[t][cur]
                    tagreg = (lane == r) ? cur : tagreg;
                }
            }
            if (lane < nn) out_tags[tlo - 1 + lane] = (float)tagreg;
        }
    } else {
        // ================= LSE + sequence-score wave =================
        float tE[16];
#pragma unroll
        for (int k = 0; k < 16; ++k) tE[k] = __expf(trans[(i0 + k) * KK + j]);

        // sequence score: strided gather prologue
        const int* tagrow = tagidx + (size_t)b * TT;
        float su = 0.0f;
#pragma unroll
        for (int c = 0; c < TT / 64; ++c) {
            int t = c * 64 + lane;
            if (t < len) {
                int tg = tagrow[t];
                su += pot[t * KK + tg];
                if (t < last) {
                    int tg2 = tagrow[t + 1];
                    su += trans[tg * KK + tg2];
                }
            }
        }
#pragma unroll
        for (int d = 1; d < 64; d <<= 1) su += __shfl_xor(su, d, 64);

        float beta = pot[j];
        float prCur = pot[min(1, last) * KK + j];
        float prN   = pot[min(2, last) * KK + j];

        for (int t = 1; t <= last; ++t) {
            float prN2 = pot[min(t + 2, last) * KK + j];

            // M = beta[lane 0]: within spread of max -> exp-safe; cancels exactly
            float M = __builtin_amdgcn_readfirstlane(beta);
            float p = __expf(beta - M);
            s_p[j] = p;                          // both halves: same addr, same data
            __builtin_amdgcn_wave_barrier();
            const float4 q0 = *(const float4*)(s_p + i0);
            const float4 q1 = *(const float4*)(s_p + i0 + 4);
            const float4 q2 = *(const float4*)(s_p + i0 + 8);
            const float4 q3 = *(const float4*)(s_p + i0 + 12);

            float a0 = fmaf(q0.x, tE[0],  q0.y * tE[1]);
            a0 = fmaf(q0.z, tE[2],  a0); a0 = fmaf(q0.w, tE[3],  a0);
            float a1 = fmaf(q1.x, tE[4],  q1.y * tE[5]);
            a1 = fmaf(q1.z, tE[6],  a1); a1 = fmaf(q1.w, tE[7],  a1);
            float a2 = fmaf(q2.x, tE[8],  q2.y * tE[9]);
            a2 = fmaf(q2.z, tE[10], a2); a2 = fmaf(q2.w, tE[11], a2);
            float a3 = fmaf(q3.x, tE[12], q3.y * tE[13]);
            a3 = fmaf(q3.z, tE[14], a3); a3 = fmaf(q3.w, tE[15], a3);
            float ssum = (a0 + a1) + (a2 + a3);
            ssum += __shfl_xor(ssum, 32, 64);    // cross-half partial (commutative)

            beta = prCur + M + __logf(ssum);
            prCur = prN; prN = prN2;
        }

        // final logsumexp (exact)
        float Mf = beta;
#pragma unroll
        for (int d = 1; d < 32; d <<= 1) Mf = fmaxf(Mf, __shfl_xor(Mf, d, 64));
        float e = __expf(beta - Mf);
#pragma unroll
        for (int d = 1; d < 32; d <<= 1) e += __shfl_xor(e, d, 64);
        float ln = Mf + __logf(e);

        if (lane == 0) out[(size_t)BB * TT + BB + b] = su - ln;  // log_likelihood
    }
}

extern "C" void kernel_launch(void* const* d_in, const int* in_sizes, int n_in,
                              void* d_out, int out_size, void* d_ws, size_t ws_size,
                              hipStream_t stream) {
    const float* potentials = (const float*)d_in[0];
    const float* transitions = (const float*)d_in[1];
    const int* sequence_lengths = (const int*)d_in[2];
    const int* tag_indices = (const int*)d_in[3];
    float* out = (float*)d_out;
    crf_kernel<<<BB, 128, 0, stream>>>(potentials, transitions, sequence_lengths,
                                       tag_indices, out);
}

// Round 4
// 428.244 us; speedup vs baseline: 5.9508x; 5.9508x over previous
//
#include <hip/hip_runtime.h>

#define BB 2048
#define TT 512
#define KK 32

// 4-source viterbi block: strict > keeps first occurrence (np.argmax semantics)
// Named scalars ONLY — local arrays with non-constant indices get demoted to
// scratch (R2 regression: 8x slowdown, VALUBusy flat, VGPR stuck at 44).
#define VBLK(q, t0, t1, t2, t3, base, m, bi) do {                       \
    float s0_ = (q).x + (t0), s1_ = (q).y + (t1);                       \
    float s2_ = (q).z + (t2), s3_ = (q).w + (t3);                       \
    m = s0_; bi = (base);                                               \
    if (s1_ > m) { m = s1_; bi = (base) + 1; }                          \
    if (s2_ > m) { m = s2_; bi = (base) + 2; }                          \
    if (s3_ > m) { m = s3_; bi = (base) + 3; }                          \
} while (0)

__launch_bounds__(128)
__global__ void crf_kernel(const float* __restrict__ pot_g,
                           const float* __restrict__ trans,
                           const int* __restrict__ seqlen,
                           const int* __restrict__ tagidx,
                           float* __restrict__ out) {
    __shared__ __align__(16) float s_a[KK];          // alpha broadcast (wave 0)
    __shared__ __align__(16) float s_p[KK];          // p broadcast (wave 1)
    __shared__ unsigned char s_bp[TT * KK];          // backpointers (wave 0)

    const int tid  = threadIdx.x;
    const int wv   = tid >> 6;
    const int lane = tid & 63;
    const int j    = lane & 31;
    const int half = lane >> 5;
    const int i0   = half << 4;
    const int b    = blockIdx.x;

    const float* pot = pot_g + (size_t)b * (TT * KK);
    const int len  = seqlen[b];
    const int last = len - 1;
    float* out_tags = out + (size_t)b * TT;

    if (wv == 0) {
        // ================= Viterbi wave =================
        float tA[16];
#pragma unroll
        for (int k = 0; k < 16; ++k) tA[k] = trans[(i0 + k) * KK + j];

        float alpha = pot[j];
        float prCur = pot[min(1, last) * KK + j];
        float prN   = pot[min(2, last) * KK + j];

        for (int t = 1; t <= last; ++t) {
            float prN2 = pot[min(t + 2, last) * KK + j];

            s_a[j] = alpha;                      // 2 lanes/addr: same data, 2-way free
            __builtin_amdgcn_wave_barrier();     // compiler fence; DS pipe in-order
            const float4 q0 = *(const float4*)(s_a + i0);
            const float4 q1 = *(const float4*)(s_a + i0 + 4);
            const float4 q2 = *(const float4*)(s_a + i0 + 8);
            const float4 q3 = *(const float4*)(s_a + i0 + 12);

            float m0, m1, m2, m3; int b0, b1, b2, b3;
            VBLK(q0, tA[0],  tA[1],  tA[2],  tA[3],  i0 + 0,  m0, b0);
            VBLK(q1, tA[4],  tA[5],  tA[6],  tA[7],  i0 + 4,  m1, b1);
            VBLK(q2, tA[8],  tA[9],  tA[10], tA[11], i0 + 8,  m2, b2);
            VBLK(q3, tA[12], tA[13], tA[14], tA[15], i0 + 12, m3, b3);
            if (m1 > m0) { m0 = m1; b0 = b1; }   // later block: strict >
            if (m3 > m2) { m2 = m3; b2 = b3; }
            if (m2 > m0) { m0 = m2; b0 = b2; }

            // cross-half: value-only shfl; winner (tie -> low half) writes bp
            float om = __shfl_xor(m0, 32, 64);
            bool won = half ? (m0 > om) : (m0 >= om);
            float mm = fmaxf(m0, om);
            if (won) s_bp[t * KK + j] = (unsigned char)b0;
            alpha = prCur + mm;                  // bit-exact recursion

            prCur = prN; prN = prN2;
        }

        // first-argmax of final alpha (replicated across halves)
        float bv = alpha; int bj = j;
#pragma unroll
        for (int d = 1; d < 32; d <<= 1) {
            float ov = __shfl_xor(bv, d, 64);
            int   oj = __shfl_xor(bj, d, 64);
            if (ov > bv || (ov == bv && oj < bj)) { bv = ov; bj = oj; }
        }
        if (lane == 0) out[(size_t)BB * TT + b] = bv;   // best_score

        for (int t = last + lane; t < TT; t += 64) out_tags[t] = (float)bj;

        // cooperative backtrace: row-loads + shfl chase, 32 steps/chunk
        __builtin_amdgcn_wave_barrier();
        int cur = bj;
        for (int thi = last; thi >= 1; thi -= 32) {
            int tlo = thi - 31; if (tlo < 1) tlo = 1;
            int nn = thi - tlo + 1;
            int rv[32];
#pragma unroll
            for (int r = 0; r < 32; ++r) {
                int t = tlo + r; t = t > thi ? thi : t;
                rv[r] = s_bp[t * KK + (lane & 31)];
            }
            int tagreg = 0;
#pragma unroll
            for (int r = 31; r >= 0; --r) {
                if (r < nn) {                       // wave-uniform predicate
                    cur = __shfl(rv[r], cur, 64);   // cur = bp[t][cur]
                    tagreg = (lane == r) ? cur : tagreg;
                }
            }
            if (lane < nn) out_tags[tlo - 1 + lane] = (float)tagreg;
        }
    } else {
        // ================= LSE + sequence-score wave =================
        float tE[16];
#pragma unroll
        for (int k = 0; k < 16; ++k) tE[k] = __expf(trans[(i0 + k) * KK + j]);

        // sequence score: strided gather prologue
        const int* tagrow = tagidx + (size_t)b * TT;
        float su = 0.0f;
#pragma unroll
        for (int c = 0; c < TT / 64; ++c) {
            int t = c * 64 + lane;
            if (t < len) {
                int tg = tagrow[t];
                su += pot[t * KK + tg];
                if (t < last) {
                    int tg2 = tagrow[t + 1];
                    su += trans[tg * KK + tg2];
                }
            }
        }
#pragma unroll
        for (int d = 1; d < 64; d <<= 1) su += __shfl_xor(su, d, 64);

        float beta = pot[j];
        float prCur = pot[min(1, last) * KK + j];
        float prN   = pot[min(2, last) * KK + j];

        for (int t = 1; t <= last; ++t) {
            float prN2 = pot[min(t + 2, last) * KK + j];

            // M = beta[lane 0]: within spread of max -> exp-safe; cancels exactly
            float M = __builtin_amdgcn_readfirstlane(beta);
            float p = __expf(beta - M);
            s_p[j] = p;
            __builtin_amdgcn_wave_barrier();
            const float4 q0 = *(const float4*)(s_p + i0);
            const float4 q1 = *(const float4*)(s_p + i0 + 4);
            const float4 q2 = *(const float4*)(s_p + i0 + 8);
            const float4 q3 = *(const float4*)(s_p + i0 + 12);

            float a0 = fmaf(q0.x, tE[0],  q0.y * tE[1]);
            a0 = fmaf(q0.z, tE[2],  a0); a0 = fmaf(q0.w, tE[3],  a0);
            float a1 = fmaf(q1.x, tE[4],  q1.y * tE[5]);
            a1 = fmaf(q1.z, tE[6],  a1); a1 = fmaf(q1.w, tE[7],  a1);
            float a2 = fmaf(q2.x, tE[8],  q2.y * tE[9]);
            a2 = fmaf(q2.z, tE[10], a2); a2 = fmaf(q2.w, tE[11], a2);
            float a3 = fmaf(q3.x, tE[12], q3.y * tE[13]);
            a3 = fmaf(q3.z, tE[14], a3); a3 = fmaf(q3.w, tE[15], a3);
            float ssum = (a0 + a1) + (a2 + a3);
            ssum += __shfl_xor(ssum, 32, 64);    // cross-half partial (commutative)

            beta = prCur + M + __logf(ssum);
            prCur = prN; prN = prN2;
        }

        // final logsumexp (exact)
        float Mf = beta;
#pragma unroll
        for (int d = 1; d < 32; d <<= 1) Mf = fmaxf(Mf, __shfl_xor(Mf, d, 64));
        float e = __expf(beta - Mf);
#pragma unroll
        for (int d = 1; d < 32; d <<= 1) e += __shfl_xor(e, d, 64);
        float ln = Mf + __logf(e);

        if (lane == 0) out[(size_t)BB * TT + BB + b] = su - ln;  // log_likelihood
    }
}

extern "C" void kernel_launch(void* const* d_in, const int* in_sizes, int n_in,
                              void* d_out, int out_size, void* d_ws, size_t ws_size,
                              hipStream_t stream) {
    const float* potentials = (const float*)d_in[0];
    const float* transitions = (const float*)d_in[1];
    const int* sequence_lengths = (const int*)d_in[2];
    const int* tag_indices = (const int*)d_in[3];
    float* out = (float*)d_out;
    crf_kernel<<<BB, 128, 0, stream>>>(potentials, transitions, sequence_lengths,
                                       tag_indices, out);
}

// Round 5
// 407.819 us; speedup vs baseline: 6.2489x; 1.0501x over previous
//
#include <hip/hip_runtime.h>

#define BB 2048
#define TT 512
#define KK 32

// 4-source viterbi block: strict > keeps first occurrence (np.argmax semantics)
// Named scalars ONLY — local arrays with non-constant indices get demoted to
// scratch (R2 regression: 8x slowdown).
#define VBLK(q, t0, t1, t2, t3, base, m, bi) do {                       \
    float s0_ = (q).x + (t0), s1_ = (q).y + (t1);                       \
    float s2_ = (q).z + (t2), s3_ = (q).w + (t3);                       \
    m = s0_; bi = (base);                                               \
    if (s1_ > m) { m = s1_; bi = (base) + 1; }                          \
    if (s2_ > m) { m = s2_; bi = (base) + 2; }                          \
    if (s3_ > m) { m = s3_; bi = (base) + 3; }                          \
} while (0)

// One viterbi step at time T consuming prefetch register PR (pot row T),
// reloading PR with pot row T+4. pot stream is HBM-resident (~900 cyc miss,
// m126); depth-4 prefetch gives ~1200 cyc headroom at ~300 cyc/step.
#define VSTEP(T, PR) do {                                               \
    float nl_ = pot[min((T) + 4, last) * KK + j];                       \
    s_a[j] = alpha;                                                     \
    __builtin_amdgcn_wave_barrier();                                    \
    const float4 q0 = *(const float4*)(s_a + i0);                       \
    const float4 q1 = *(const float4*)(s_a + i0 + 4);                   \
    const float4 q2 = *(const float4*)(s_a + i0 + 8);                   \
    const float4 q3 = *(const float4*)(s_a + i0 + 12);                  \
    float m0, m1, m2, m3; int b0, b1, b2, b3;                           \
    VBLK(q0, tA[0],  tA[1],  tA[2],  tA[3],  i0 + 0,  m0, b0);          \
    VBLK(q1, tA[4],  tA[5],  tA[6],  tA[7],  i0 + 4,  m1, b1);          \
    VBLK(q2, tA[8],  tA[9],  tA[10], tA[11], i0 + 8,  m2, b2);          \
    VBLK(q3, tA[12], tA[13], tA[14], tA[15], i0 + 12, m3, b3);          \
    if (m1 > m0) { m0 = m1; b0 = b1; }                                  \
    if (m3 > m2) { m2 = m3; b2 = b3; }                                  \
    if (m2 > m0) { m0 = m2; b0 = b2; }                                  \
    float om = __shfl_xor(m0, 32, 64);                                  \
    bool won = half ? (m0 > om) : (m0 >= om);                           \
    float mm = fmaxf(m0, om);                                           \
    if (won) s_bp[(T) * KK + j] = (unsigned char)b0;                    \
    alpha = PR + mm;                                                    \
    PR = nl_;                                                           \
} while (0)

// One LSE step at time T consuming PR, reloading PR with pot row T+4.
#define LSTEP(T, PR) do {                                               \
    float nl_ = pot[min((T) + 4, last) * KK + j];                       \
    float M = __builtin_amdgcn_readfirstlane(beta);                     \
    float p = __expf(beta - M);                                         \
    s_p[j] = p;                                                         \
    __builtin_amdgcn_wave_barrier();                                    \
    const float4 q0 = *(const float4*)(s_p + i0);                       \
    const float4 q1 = *(const float4*)(s_p + i0 + 4);                   \
    const float4 q2 = *(const float4*)(s_p + i0 + 8);                   \
    const float4 q3 = *(const float4*)(s_p + i0 + 12);                  \
    float a0 = fmaf(q0.x, tE[0],  q0.y * tE[1]);                        \
    a0 = fmaf(q0.z, tE[2],  a0); a0 = fmaf(q0.w, tE[3],  a0);           \
    float a1 = fmaf(q1.x, tE[4],  q1.y * tE[5]);                        \
    a1 = fmaf(q1.z, tE[6],  a1); a1 = fmaf(q1.w, tE[7],  a1);           \
    float a2 = fmaf(q2.x, tE[8],  q2.y * tE[9]);                        \
    a2 = fmaf(q2.z, tE[10], a2); a2 = fmaf(q2.w, tE[11], a2);           \
    float a3 = fmaf(q3.x, tE[12], q3.y * tE[13]);                       \
    a3 = fmaf(q3.z, tE[14], a3); a3 = fmaf(q3.w, tE[15], a3);           \
    float ssum = (a0 + a1) + (a2 + a3);                                 \
    ssum += __shfl_xor(ssum, 32, 64);                                   \
    beta = PR + M + __logf(ssum);                                       \
    PR = nl_;                                                           \
} while (0)

__launch_bounds__(128)
__global__ void crf_kernel(const float* __restrict__ pot_g,
                           const float* __restrict__ trans,
                           const int* __restrict__ seqlen,
                           const int* __restrict__ tagidx,
                           float* __restrict__ out) {
    __shared__ __align__(16) float s_a[KK];          // alpha broadcast (wave 0)
    __shared__ __align__(16) float s_p[KK];          // p broadcast (wave 1)
    __shared__ unsigned char s_bp[TT * KK];          // backpointers (wave 0)

    const int tid  = threadIdx.x;
    const int wv   = tid >> 6;
    const int lane = tid & 63;
    const int j    = lane & 31;
    const int half = lane >> 5;
    const int i0   = half << 4;
    const int b    = blockIdx.x;

    const float* pot = pot_g + (size_t)b * (TT * KK);
    const int len  = seqlen[b];
    const int last = len - 1;
    float* out_tags = out + (size_t)b * TT;

    if (wv == 0) {
        // ================= Viterbi wave =================
        float tA[16];
#pragma unroll
        for (int k = 0; k < 16; ++k) tA[k] = trans[(i0 + k) * KK + j];

        float alpha = pot[j];
        float pr0 = pot[min(1, last) * KK + j];
        float pr1 = pot[min(2, last) * KK + j];
        float pr2 = pot[min(3, last) * KK + j];
        float pr3 = pot[min(4, last) * KK + j];

        int t = 1;
        for (; t + 3 <= last; t += 4) {
            VSTEP(t,     pr0);
            VSTEP(t + 1, pr1);
            VSTEP(t + 2, pr2);
            VSTEP(t + 3, pr3);
        }
        if (t <= last) { VSTEP(t, pr0); ++t; }
        if (t <= last) { VSTEP(t, pr1); ++t; }
        if (t <= last) { VSTEP(t, pr2); ++t; }

        // first-argmax of final alpha (replicated across halves)
        float bv = alpha; int bj = j;
#pragma unroll
        for (int d = 1; d < 32; d <<= 1) {
            float ov = __shfl_xor(bv, d, 64);
            int   oj = __shfl_xor(bj, d, 64);
            if (ov > bv || (ov == bv && oj < bj)) { bv = ov; bj = oj; }
        }
        if (lane == 0) out[(size_t)BB * TT + b] = bv;   // best_score

        for (int tt = last + lane; tt < TT; tt += 64) out_tags[tt] = (float)bj;

        // cooperative backtrace: row-loads + shfl chase, 32 steps/chunk
        __builtin_amdgcn_wave_barrier();
        int cur = bj;
        for (int thi = last; thi >= 1; thi -= 32) {
            int tlo = thi - 31; if (tlo < 1) tlo = 1;
            int nn = thi - tlo + 1;
            int rv[32];
#pragma unroll
            for (int r = 0; r < 32; ++r) {
                int tt = tlo + r; tt = tt > thi ? thi : tt;
                rv[r] = s_bp[tt * KK + (lane & 31)];
            }
            int tagreg = 0;
#pragma unroll
            for (int r = 31; r >= 0; --r) {
                if (r < nn) {                       // wave-uniform predicate
                    cur = __shfl(rv[r], cur, 64);   // cur = bp[t][cur]
                    tagreg = (lane == r) ? cur : tagreg;
                }
            }
            if (lane < nn) out_tags[tlo - 1 + lane] = (float)tagreg;
        }
    } else {
        // ================= LSE + sequence-score wave =================
        float tE[16];
#pragma unroll
        for (int k = 0; k < 16; ++k) tE[k] = __expf(trans[(i0 + k) * KK + j]);

        // sequence score: strided gather prologue
        const int* tagrow = tagidx + (size_t)b * TT;
        float su = 0.0f;
#pragma unroll
        for (int c = 0; c < TT / 64; ++c) {
            int tt = c * 64 + lane;
            if (tt < len) {
                int tg = tagrow[tt];
                su += pot[tt * KK + tg];
                if (tt < last) {
                    int tg2 = tagrow[tt + 1];
                    su += trans[tg * KK + tg2];
                }
            }
        }
#pragma unroll
        for (int d = 1; d < 64; d <<= 1) su += __shfl_xor(su, d, 64);

        float beta = pot[j];
        float pr0 = pot[min(1, last) * KK + j];
        float pr1 = pot[min(2, last) * KK + j];
        float pr2 = pot[min(3, last) * KK + j];
        float pr3 = pot[min(4, last) * KK + j];

        int t = 1;
        for (; t + 3 <= last; t += 4) {
            LSTEP(t,     pr0);
            LSTEP(t + 1, pr1);
            LSTEP(t + 2, pr2);
            LSTEP(t + 3, pr3);
        }
        if (t <= last) { LSTEP(t, pr0); ++t; }
        if (t <= last) { LSTEP(t, pr1); ++t; }
        if (t <= last) { LSTEP(t, pr2); ++t; }

        // final logsumexp (exact)
        float Mf = beta;
#pragma unroll
        for (int d = 1; d < 32; d <<= 1) Mf = fmaxf(Mf, __shfl_xor(Mf, d, 64));
        float e = __expf(beta - Mf);
#pragma unroll
        for (int d = 1; d < 32; d <<= 1) e += __shfl_xor(e, d, 64);
        float ln = Mf + __logf(e);

        if (lane == 0) out[(size_t)BB * TT + BB + b] = su - ln;  // log_likelihood
    }
}

extern "C" void kernel_launch(void* const* d_in, const int* in_sizes, int n_in,
                              void* d_out, int out_size, void* d_ws, size_t ws_size,
                              hipStream_t stream) {
    const float* potentials = (const float*)d_in[0];
    const float* transitions = (const float*)d_in[1];
    const int* sequence_lengths = (const int*)d_in[2];
    const int* tag_indices = (const int*)d_in[3];
    float* out = (float*)d_out;
    crf_kernel<<<BB, 128, 0, stream>>>(potentials, transitions, sequence_lengths,
                                       tag_indices, out);
}